// Round 17
// baseline (490.454 us; speedup 1.0000x reference)
//
#include <hip/hip_runtime.h>

// ---------------------------------------------------------------------------
// TransformerBlock: B=8, T=1024, E=1024, H=16, HS=64, FF=4096
// bf16 MFMA (16x16x32) everywhere; bf16x3 split (hi/lo) on LN1->Q,K and QK^T
// because the reference scales scores by sqrt(T)=32 (near-one-hot softmax).
// R17: gemm_bt BKT 32->64 (halves barrier events per K at unchanged
// occupancy: LDS 16->32KB, regs ~108 < (256,2) cap). Serves ffn2 (K=4096,
// 64->32 iters), proj, vgemm. Everything else identical to R16 (486us).
// ---------------------------------------------------------------------------

typedef unsigned short u16;
typedef __attribute__((ext_vector_type(8))) short  bfx8;
typedef __attribute__((ext_vector_type(4))) float  f32x4;
typedef __attribute__((ext_vector_type(4))) unsigned short u16v4;

#define MFMA16 __builtin_amdgcn_mfma_f32_16x16x32_bf16

__device__ __forceinline__ u16 f2bf(float f) {
    union { float f; unsigned u; } c; c.f = f;
    unsigned r = c.u + 0x7fffu + ((c.u >> 16) & 1u);
    return (u16)(r >> 16);
}
__device__ __forceinline__ float bf2f(u16 b) {
    union { unsigned u; float f; } c; c.u = ((unsigned)b) << 16; return c.f;
}
__device__ __forceinline__ float exp2_fast(float x) {
    float r; asm("v_exp_f32 %0, %1" : "=v"(r) : "v"(x)); return r;
}

__device__ __forceinline__ void gl_lds16(const void* g, void* l) {
    void* gg = (void*)g;
    __builtin_amdgcn_global_load_lds(
        (__attribute__((address_space(1))) void*)gg,
        (__attribute__((address_space(3))) void*)l,
        16, 0, 0);
}

// ---------------------------------------------------------------------------
// Shared transpose body: one 64x64 tile. src f32 [R][C] row-major at
// (row0,col0); dst bf16 [C][R] with row stride OS at (col0,row0).
// ---------------------------------------------------------------------------
__device__ __forceinline__ void transpose_tile(const float* __restrict__ src,
                                               u16* __restrict__ dhi,
                                               u16* __restrict__ dlo,
                                               int C, int OS, int row0, int col0)
{
    __shared__ float t[64][65];
    const int tid = threadIdx.x;
    const float* s = src + ((size_t)row0) * C + col0;
    const size_t obase = ((size_t)col0) * OS + row0;
    {
        const int r = tid >> 2, c4 = (tid & 3) * 16;
#pragma unroll
        for (int k = 0; k < 4; ++k) {
            float4 f = *(const float4*)(s + (size_t)r * C + c4 + k * 4);
            t[r][c4 + k*4 + 0] = f.x; t[r][c4 + k*4 + 1] = f.y;
            t[r][c4 + k*4 + 2] = f.z; t[r][c4 + k*4 + 3] = f.w;
        }
    }
    __syncthreads();
    {
        const int c = tid >> 2, r4 = (tid & 3) * 16;
        bfx8 h0, h1, l0, l1;
#pragma unroll
        for (int k = 0; k < 8; ++k) {
            float v0 = t[r4 + k][c];
            float v1 = t[r4 + 8 + k][c];
            u16 a = f2bf(v0), b = f2bf(v1);
            h0[k] = (short)a; h1[k] = (short)b;
            l0[k] = (short)f2bf(v0 - bf2f(a));
            l1[k] = (short)f2bf(v1 - bf2f(b));
        }
        u16* d = dhi + obase + (size_t)c * OS + r4;
        *(bfx8*)d = h0; *(bfx8*)(d + 8) = h1;
        if (dlo) {
            u16* d2 = dlo + obase + (size_t)c * OS + r4;
            *(bfx8*)d2 = l0; *(bfx8*)(d2 + 8) = l1;
        }
    }
}

// ---------------------------------------------------------------------------
// repack_qkv: wq/wk/wv [H=16][E=1024][HS=64] -> wqkT_hi/lo rows 0..2047 and
// wvT (no split). Grid (3, 16 row-tiles, 16 heads); x selects the weight.
// ---------------------------------------------------------------------------
__global__ __launch_bounds__(256)
void repack_qkv(const float* __restrict__ wq, const float* __restrict__ wk,
                const float* __restrict__ wv, u16* __restrict__ qkhi,
                u16* __restrict__ qklo, u16* __restrict__ vT)
{
    const int sel = blockIdx.x;       // 0=wq 1=wk 2=wv
    const int yt  = blockIdx.y;
    const int hh  = blockIdx.z;
    const float* src = (sel == 0) ? wq : (sel == 1) ? wk : wv;
    u16* dhi = (sel == 0) ? qkhi : (sel == 1) ? (qkhi + (size_t)1024 * 1024) : vT;
    u16* dlo = (sel == 0) ? qklo : (sel == 1) ? (qklo + (size_t)1024 * 1024) : nullptr;
    transpose_tile(src + (size_t)hh * 65536,
                   dhi + (size_t)hh * 65536,
                   dlo ? dlo + (size_t)hh * 65536 : nullptr,
                   64, 1024, yt * 64, 0);
}

// ---------------------------------------------------------------------------
// repack_w: w_proj (256 tiles) + w1 (1024) + w2 (1024). Flat 2304-block grid.
// ---------------------------------------------------------------------------
__global__ __launch_bounds__(256)
void repack_w(const float* __restrict__ wp, u16* __restrict__ wpT,
              const float* __restrict__ w1, u16* __restrict__ w1T,
              const float* __restrict__ w2, u16* __restrict__ w2T)
{
    const int id = blockIdx.x;
    if (id < 256) {
        const int xt = id & 15, yt = id >> 4;
        transpose_tile(wp, wpT, nullptr, 1024, 1024, yt * 64, xt * 64);
    } else if (id < 1280) {
        const int i2 = id - 256;
        const int xt = i2 & 63, yt = i2 >> 6;
        transpose_tile(w1, w1T, nullptr, 4096, 1024, yt * 64, xt * 64);
    } else {
        const int i2 = id - 1280;
        const int xt = i2 & 15, yt = i2 >> 4;
        transpose_tile(w2, w2T, nullptr, 1024, 4096, yt * 64, xt * 64);
    }
}

// ---------------------------------------------------------------------------
// LayerNorm over E=1024. 4 rows per 256-thr block, one wave per row.
// ---------------------------------------------------------------------------
__global__ __launch_bounds__(256)
void ln_split(const float* __restrict__ x, const float* __restrict__ g,
              const float* __restrict__ be, u16* __restrict__ hhi,
              u16* __restrict__ hlo)
{
    const int lane = threadIdx.x & 63;
    const int row  = blockIdx.x * 4 + (threadIdx.x >> 6);
    const float* xr = x + (size_t)row * 1024;

    float4 v[4];
    float s = 0.f, s2 = 0.f;
#pragma unroll
    for (int i = 0; i < 4; ++i) {
        v[i] = *(const float4*)(xr + i * 256 + lane * 4);
        s  += v[i].x + v[i].y + v[i].z + v[i].w;
        s2 += v[i].x*v[i].x + v[i].y*v[i].y + v[i].z*v[i].z + v[i].w*v[i].w;
    }
#pragma unroll
    for (int m = 32; m >= 1; m >>= 1) {
        s  += __shfl_xor(s,  m, 64);
        s2 += __shfl_xor(s2, m, 64);
    }
    const float mean = s * (1.0f / 1024.0f);
    const float var  = s2 * (1.0f / 1024.0f) - mean * mean;
    const float inv  = rsqrtf(var + 1e-5f);

#pragma unroll
    for (int i = 0; i < 4; ++i) {
        const int col0 = i * 256 + lane * 4;
        float hv[4];
        hv[0] = (v[i].x - mean) * inv * g[col0+0] + be[col0+0];
        hv[1] = (v[i].y - mean) * inv * g[col0+1] + be[col0+1];
        hv[2] = (v[i].z - mean) * inv * g[col0+2] + be[col0+2];
        hv[3] = (v[i].w - mean) * inv * g[col0+3] + be[col0+3];
        u16v4 hb, lb;
#pragma unroll
        for (int k = 0; k < 4; ++k) {
            u16 a = f2bf(hv[k]);
            hb[k] = a;
            lb[k] = f2bf(hv[k] - bf2f(a));
        }
        *(u16v4*)(hhi + (size_t)row * 1024 + col0) = hb;
        if (hlo) *(u16v4*)(hlo + (size_t)row * 1024 + col0) = lb;
    }
}

// ---------------------------------------------------------------------------
// GEMM (m97 128x128, R17: BKT=64): C = A @ Bt^T.
// FLAGS: 1=bias 2=relu 4=residual 8=f32out 16=vT-scatter.
// T1 bijective XCD-chunked block swizzle (nwg % 8 == 0).
// LDS 32KB (still >=2 blocks/CU); 32 MFMA + 1 barrier pair per 64-K step.
// ---------------------------------------------------------------------------
#define BM 128
#define BN 128
#define BKT 64

template<int FLAGS>
__global__ __launch_bounds__(256, 2)
void gemm_bt(const u16* __restrict__ A, const u16* __restrict__ Bt,
             void* __restrict__ Cout, const float* __restrict__ bias,
             const float* __restrict__ res, int M, int N, int K)
{
    __shared__ u16 As[BM * BKT];
    __shared__ u16 Bs[BN * BKT];
    const int tid  = threadIdx.x;
    const int lane = tid & 63, wave = tid >> 6;
    const int wr = wave >> 1, wc = wave & 1;
    const int li = lane & 15, lg = lane >> 4;

    const int nbx = gridDim.x;
    const int nwg = nbx * gridDim.y;
    const int cpx = nwg >> 3;
    int bid = blockIdx.y * nbx + blockIdx.x;
    bid = (bid & 7) * cpx + (bid >> 3);
    const size_t m0 = (size_t)(bid / nbx) * BM;
    const size_t n0 = (size_t)(bid % nbx) * BN;
    f32x4 acc[4][4] = {};

    // staging: 128 rows x 64 cols = 1024 slots of 8 elems; 4 slots/thread
    for (int kt = 0; kt < K; kt += BKT) {
        __syncthreads();
#pragma unroll
        for (int site = 0; site < 4; ++site) {
            const int s = tid + site * 256;
            const int r = s >> 3, kc = (s & 7) * 8;
            gl_lds16(A  + (m0 + r) * K + kt + kc, As + s * 8);
            gl_lds16(Bt + (n0 + r) * K + kt + kc, Bs + s * 8);
        }
        __syncthreads();
        bfx8 af[4][2], bfr[4][2];
#pragma unroll
        for (int i = 0; i < 4; ++i) {
            const int rb = (wr * 64 + i * 16 + li) * BKT;
            af[i][0] = *(const bfx8*)&As[rb + lg * 8];
            af[i][1] = *(const bfx8*)&As[rb + 32 + lg * 8];
        }
#pragma unroll
        for (int j = 0; j < 4; ++j) {
            const int rb = (wc * 64 + j * 16 + li) * BKT;
            bfr[j][0] = *(const bfx8*)&Bs[rb + lg * 8];
            bfr[j][1] = *(const bfx8*)&Bs[rb + 32 + lg * 8];
        }
#pragma unroll
        for (int ks = 0; ks < 2; ++ks)
#pragma unroll
            for (int i = 0; i < 4; ++i)
#pragma unroll
                for (int j = 0; j < 4; ++j)
                    acc[i][j] = MFMA16(af[i][ks], bfr[j][ks], acc[i][j], 0, 0, 0);
    }

    float* Cf = (float*)Cout;
    u16*   Cb = (u16*)Cout;
#pragma unroll
    for (int i = 0; i < 4; ++i)
#pragma unroll
        for (int j = 0; j < 4; ++j)
#pragma unroll
            for (int r = 0; r < 4; ++r) {
                const size_t row = m0 + wr * 64 + i * 16 + lg * 4 + r;
                const size_t col = n0 + wc * 64 + j * 16 + li;
                float v = acc[i][j][r];
                if (FLAGS & 1) v += bias[col];
                if (FLAGS & 2) v = fmaxf(v, 0.0f);
                if (FLAGS & 4) v += res[row * (size_t)N + col];
                if (FLAGS & 16) {
                    const size_t drow = ((col >> 10) * 16 + (row >> 6)) * 64 + (row & 63);
                    Cb[drow * 1024 + (col & 1023)] = f2bf(v);
                } else if (FLAGS & 8) {
                    Cf[row * (size_t)N + col] = v;
                } else {
                    Cb[row * (size_t)N + col] = f2bf(v);
                }
            }
}

// ---------------------------------------------------------------------------
// 8-phase 256x256 GEMM core (T2+T3+T4+T5). EPI: 0 = bias+relu bf16 out,
// 1 = hi/lo split bf16 out. SPLIT3: fold bf16x3 into K'=3K with passes
// INTERLEAVED per k (j -> k=j/3, p=j%3).
// ---------------------------------------------------------------------------
template<int EPI, int SPLIT3>
__global__ __launch_bounds__(512, 2)
void gemm8(const u16* __restrict__ A, const u16* __restrict__ Al,
           const u16* __restrict__ Bt, const u16* __restrict__ Bl,
           u16* __restrict__ C, u16* __restrict__ Clo,
           const float* __restrict__ bias,
           int M, int N, int K, int NBX)
{
    __shared__ u16 Asl[2][2][128 * 64];
    __shared__ u16 Bsl[2][2][128 * 64];
    const int tid = threadIdx.x;
    const int lane = tid & 63, wave = tid >> 6;
    const int wr = wave >> 2, wc = wave & 3;
    const int li = lane & 15, lg = lane >> 4;

    const int bid = blockIdx.x;
    const int nwg = gridDim.x;
    const int cpx = nwg >> 3;
    const int swz = (bid & 7) * cpx + (bid >> 3);
    const int bx = swz % NBX, by = swz / NBX;
    const size_t m0 = (size_t)by * 256, n0 = (size_t)bx * 256;

    char* ldsA = (char*)&Asl[0][0][0];
    char* ldsB = (char*)&Bsl[0][0][0];

    const int KT = K >> 6;

    auto stageA = [&](int j, int h) {
        const u16* src = A;
        int jj = j;
        if (SPLIT3) {
            const int k = j / 3, p = j - 3 * k;
            src = (p == 2) ? Al : A;
            jj = k;
        }
#pragma unroll
        for (int site = 0; site < 2; ++site) {
            const int s = tid + site * 512;
            const int r = s >> 3;
            const int cb = ((s & 7) << 4) ^ ((r & 7) << 4);
            gl_lds16((const char*)(src + (m0 + h * 128 + r) * (size_t)K + (size_t)jj * 64) + cb,
                     ldsA + ((j & 1) * 2 + h) * 16384 + s * 16);
        }
    };
    auto stageB = [&](int j, int h) {
        const u16* src = Bt;
        int jj = j;
        if (SPLIT3) {
            const int k = j / 3, p = j - 3 * k;
            src = (p == 1) ? Bl : Bt;
            jj = k;
        }
#pragma unroll
        for (int site = 0; site < 2; ++site) {
            const int s = tid + site * 512;
            const int r = s >> 3;
            const int cb = ((s & 7) << 4) ^ ((r & 7) << 4);
            gl_lds16((const char*)(src + (n0 + h * 128 + r) * (size_t)K + (size_t)jj * 64) + cb,
                     ldsB + ((j & 1) * 2 + h) * 16384 + s * 16);
        }
    };

    const int lsw = (li & 7) << 4;
    const int aHalfBase = wr * 16384;
    const int bHalfBase = (wc >> 1) * 16384;
    const int bRow0 = (wc & 1) * 64;

    f32x4 acc[8][4] = {};
    const int NT = SPLIT3 ? 3 * KT : KT;
    const int NI = NT >> 1;

    stageA(0, 0); stageA(0, 1); stageB(0, 0); stageB(0, 1);
    stageB(1, 0); stageB(1, 1);
    asm volatile("s_waitcnt vmcnt(0)" ::: "memory");
    __builtin_amdgcn_sched_barrier(0);
    __builtin_amdgcn_s_barrier();
    __builtin_amdgcn_sched_barrier(0);

    for (int t = 0; t < NI; ++t) {
        const bool more = (t + 1 < NI);
#pragma unroll
        for (int half = 0; half < 2; ++half) {
            const int buf = half;
            const int abase = buf * 32768 + aHalfBase;
            const int bbase = buf * 32768 + bHalfBase;
            bfx8 bfr[4][2];
#pragma unroll
            for (int q = 0; q < 4; ++q) {
                if (q == 0) {
#pragma unroll
                    for (int nf = 0; nf < 4; ++nf)
#pragma unroll
                        for (int ks = 0; ks < 2; ++ks)
                            bfr[nf][ks] = *(const bfx8*)(ldsB + bbase
                                + (bRow0 + nf * 16 + li) * 128
                                + ((ks * 64 + lg * 16) ^ lsw));
                }
                bfx8 afr[2][2];
#pragma unroll
                for (int m = 0; m < 2; ++m)
#pragma unroll
                    for (int ks = 0; ks < 2; ++ks)
                        afr[m][ks] = *(const bfx8*)(ldsA + abase
                            + ((2 * q + m) * 16 + li) * 128
                            + ((ks * 64 + lg * 16) ^ lsw));

                if (half == 0) {
                    if (q == 0) stageA(2 * t + 1, 0);
                    else if (q == 1) stageA(2 * t + 1, 1);
                    else if (q == 2) { if (more) stageB(2 * t + 2, 0); }
                    else             { if (more) stageB(2 * t + 2, 1); }
                } else {
                    if (q == 0)      { if (more) stageA(2 * t + 2, 0); }
                    else if (q == 1) { if (more) stageA(2 * t + 2, 1); }
                    else if (q == 2) { if (more) stageB(2 * t + 3, 0); }
                    else             { if (more) stageB(2 * t + 3, 1); }
                }

                __builtin_amdgcn_sched_barrier(0);
                __builtin_amdgcn_s_barrier();
                asm volatile("s_waitcnt lgkmcnt(0)" ::: "memory");
                __builtin_amdgcn_sched_barrier(0);
                __builtin_amdgcn_s_setprio(1);
#pragma unroll
                for (int ks = 0; ks < 2; ++ks)
#pragma unroll
                    for (int m = 0; m < 2; ++m)
#pragma unroll
                        for (int nf = 0; nf < 4; ++nf)
                            acc[2 * q + m][nf] = MFMA16(afr[m][ks], bfr[nf][ks],
                                                        acc[2 * q + m][nf], 0, 0, 0);
                __builtin_amdgcn_s_setprio(0);
                __builtin_amdgcn_sched_barrier(0);
                if (q == 3) {
                    if (half == 0) {
                        if (more) { asm volatile("s_waitcnt vmcnt(4)" ::: "memory"); }
                        else      { asm volatile("s_waitcnt vmcnt(0)" ::: "memory"); }
                    } else if (more) {
                        asm volatile("s_waitcnt vmcnt(4)" ::: "memory");
                    }
                    __builtin_amdgcn_sched_barrier(0);
                }
                __builtin_amdgcn_s_barrier();
                __builtin_amdgcn_sched_barrier(0);
            }
        }
    }

#pragma unroll
    for (int i = 0; i < 8; ++i)
#pragma unroll
        for (int nf = 0; nf < 4; ++nf)
#pragma unroll
            for (int r = 0; r < 4; ++r) {
                const size_t row = m0 + wr * 128 + i * 16 + lg * 4 + r;
                const size_t col = n0 + wc * 64 + nf * 16 + li;
                if (EPI == 0) {
                    float v = acc[i][nf][r] + bias[col];
                    v = fmaxf(v, 0.0f);
                    C[row * (size_t)N + col] = f2bf(v);
                } else {
                    const float v = acc[i][nf][r];
                    const u16 hi = f2bf(v);
                    C[row * (size_t)N + col]   = hi;
                    Clo[row * (size_t)N + col] = f2bf(v - bf2f(hi));
                }
            }
}

// ---------------------------------------------------------------------------
// Causal flash attention (R13 config, proven ~120us), 4 waves / 64 Q-rows,
// 2048 blocks, XCD-chunked + qt-reversed. Q/K from STACKED qk buffers
// (row stride 2048). K hi/lo double-buffered in LDS (XOR swizzle);
// V -> regs at iter top; counted vmcnt; l via ones-MFMA; defer-max;
// Pl swizzled [64][64]. LDS 40960 -> 3 blocks/CU. (256,3): lower caps
// spill (R5-R7); bigger tiles lose occupancy (R14).
// ---------------------------------------------------------------------------
#define QKS 2048

__global__ __launch_bounds__(256, 3)
void attn(const u16* __restrict__ qkhi, const u16* __restrict__ qklo,
          const u16* __restrict__ vt, u16* __restrict__ ao)
{
    const int id  = blockIdx.x;
    const int swz = (id & 7) * 256 + (id >> 3);
    const int qt  = 15 - (swz & 15);
    const int h   = (swz >> 4) & 15;
    const int b   = swz >> 8;

    const int tid = threadIdx.x;
    const int wave = tid >> 6, lane = tid & 63;
    const int li = lane & 15, lg = lane >> 4;

    __shared__ u16 KsHi[2][4096];
    __shared__ u16 KsLo[2][4096];
    __shared__ u16 Pl[64 * 64];

    const size_t qrow = (size_t)b * 1024 + qt * 64 + wave * 16 + li;
    const size_t qoff = qrow * QKS + h * 64 + lg * 8;
    const bfx8 qh0 = *(const bfx8*)(qkhi + qoff);
    const bfx8 qh1 = *(const bfx8*)(qkhi + qoff + 32);
    const bfx8 ql0 = *(const bfx8*)(qklo + qoff);
    const bfx8 ql1 = *(const bfx8*)(qklo + qoff + 32);

    bfx8 onesf;
#pragma unroll
    for (int k = 0; k < 8; ++k) onesf[k] = (short)0x3F80;

    f32x4 O[4] = {};
    f32x4 O5 = {0.f, 0.f, 0.f, 0.f};
    float mrow[4] = {-3e38f, -3e38f, -3e38f, -3e38f};

    const u16* kh_base = qkhi + ((size_t)b * 1024) * QKS + 1024 + h * 64;
    const u16* kl_base = qklo + ((size_t)b * 1024) * QKS + 1024 + h * 64;
    const u16* v_base  = vt + ((size_t)(b * 16 + h) * 64) * 1024;

    auto stageK = [&](int kt, int bufIdx) {
#pragma unroll
        for (int site = 0; site < 2; ++site) {
            const int s = tid + site * 256;
            const int r = s >> 3;
            const int cb = (((s & 7) << 4) ^ ((r & 7) << 4));
            const size_t go = ((size_t)(kt * 64 + r)) * QKS;
            gl_lds16((const char*)(kh_base + go) + cb, (char*)&KsHi[bufIdx][0] + s * 16);
            gl_lds16((const char*)(kl_base + go) + cb, (char*)&KsLo[bufIdx][0] + s * 16);
        }
    };

    const int rswz = (li & 7) << 4;
    char* pband = (char*)&Pl[0] + wave * 2048;

    stageK(0, 0);

    for (int kt = 0; kt <= qt; ++kt) {
        const int cur = kt & 1;

        bfx8 vld[2][4];
#pragma unroll
        for (int nf = 0; nf < 4; ++nf) {
            const u16* vr = v_base + ((size_t)(nf * 16 + li)) * 1024 + kt * 64 + lg * 8;
            vld[0][nf] = *(const bfx8*)vr;
            vld[1][nf] = *(const bfx8*)(vr + 32);
        }

        if (kt < qt) {
            stageK(kt + 1, cur ^ 1);
            asm volatile("s_waitcnt vmcnt(12)" ::: "memory");
        } else {
            asm volatile("s_waitcnt vmcnt(8)" ::: "memory");
        }
        __builtin_amdgcn_sched_barrier(0);
        __builtin_amdgcn_s_barrier();
        __builtin_amdgcn_sched_barrier(0);

        float sv[4][4];
        const char* khc = (const char*)&KsHi[cur][0];
        const char* klc = (const char*)&KsLo[cur][0];
#pragma unroll
        for (int nf = 0; nf < 4; ++nf) {
            const int rb = (nf * 16 + li) * 128;
            bfx8 kh0v = *(const bfx8*)(khc + rb + (((lg * 16) + 0 ) ^ rswz));
            bfx8 kh1v = *(const bfx8*)(khc + rb + (((lg * 16) + 64) ^ rswz));
            bfx8 kl0v = *(const bfx8*)(klc + rb + (((lg * 16) + 0 ) ^ rswz));
            bfx8 kl1v = *(const bfx8*)(klc + rb + (((lg * 16) + 64) ^ rswz));
            f32x4 a = {0.f, 0.f, 0.f, 0.f};
            a = MFMA16(qh0, kh0v, a, 0, 0, 0);
            a = MFMA16(qh1, kh1v, a, 0, 0, 0);
            a = MFMA16(qh0, kl0v, a, 0, 0, 0);
            a = MFMA16(qh1, kl1v, a, 0, 0, 0);
            a = MFMA16(ql0, kh0v, a, 0, 0, 0);
            a = MFMA16(ql1, kh1v, a, 0, 0, 0);
#pragma unroll
            for (int r = 0; r < 4; ++r) sv[nf][r] = a[r];
        }

        asm volatile("s_waitcnt lgkmcnt(0)" ::: "memory");
        __builtin_amdgcn_sched_barrier(0);
        __builtin_amdgcn_s_barrier();
        __builtin_amdgcn_sched_barrier(0);

        const float SC = 46.16624130844683f;
        float pmax[4] = {-3e38f, -3e38f, -3e38f, -3e38f};
        if (kt == qt) {
            const int rowg = qt * 64 + wave * 16 + lg * 4;
            const int colg = kt * 64 + li;
#pragma unroll
            for (int nf = 0; nf < 4; ++nf)
#pragma unroll
                for (int r = 0; r < 4; ++r) {
                    float x2 = sv[nf][r] * SC;
                    if (colg + nf * 16 > rowg + r) x2 = -3e38f;
                    sv[nf][r] = x2;
                    pmax[r] = fmaxf(pmax[r], x2);
                }
        } else {
#pragma unroll
            for (int nf = 0; nf < 4; ++nf)
#pragma unroll
                for (int r = 0; r < 4; ++r) {
                    const float x2 = sv[nf][r] * SC;
                    sv[nf][r] = x2;
                    pmax[r] = fmaxf(pmax[r], x2);
                }
        }
#pragma unroll
        for (int msk = 1; msk < 16; msk <<= 1)
#pragma unroll
            for (int r = 0; r < 4; ++r)
                pmax[r] = fmaxf(pmax[r], __shfl_xor(pmax[r], msk, 64));

        const bool grow = !__all((pmax[0] - mrow[0] <= 11.5416f) &&
                                 (pmax[1] - mrow[1] <= 11.5416f) &&
                                 (pmax[2] - mrow[2] <= 11.5416f) &&
                                 (pmax[3] - mrow[3] <= 11.5416f));
        if (grow) {
            float alr[4];
#pragma unroll
            for (int r = 0; r < 4; ++r) {
                const float mnew = fmaxf(mrow[r], pmax[r]);
                alr[r] = exp2_fast(mrow[r] - mnew);
                mrow[r] = mnew;
            }
#pragma unroll
            for (int nf = 0; nf < 4; ++nf)
#pragma unroll
                for (int r = 0; r < 4; ++r)
                    O[nf][r] *= alr[r];
#pragma unroll
            for (int r = 0; r < 4; ++r)
                O5[r] *= alr[r];
        }

#pragma unroll
        for (int nf = 0; nf < 4; ++nf)
#pragma unroll
            for (int r = 0; r < 4; ++r) {
                const int prow = lg * 4 + r;
                const int pb = prow * 128 + ((((nf * 16 + li) * 2)) ^ ((prow & 7) << 4));
                *(u16*)(pband + pb) = f2bf(exp2_fast(sv[nf][r] - mrow[r]));
            }

#pragma unroll
        for (int ku = 0; ku < 2; ++ku) {
            bfx8 pf = *(const bfx8*)(pband + li * 128
                                     + ((ku * 64 + lg * 16) ^ ((li & 7) << 4)));
#pragma unroll
            for (int nf = 0; nf < 4; ++nf)
                O[nf] = MFMA16(pf, vld[ku][nf], O[nf], 0, 0, 0);
            O5 = MFMA16(pf, onesf, O5, 0, 0, 0);
        }
    }

    float invl[4];
#pragma unroll
    for (int r = 0; r < 4; ++r) invl[r] = 1.0f / O5[r];
    const size_t orow = (size_t)b * 1024 + qt * 64 + wave * 16 + lg * 4;
#pragma unroll
    for (int nf = 0; nf < 4; ++nf)
#pragma unroll
        for (int r = 0; r < 4; ++r)
            ao[(orow + r) * 1024 + h * 64 + nf * 16 + li] = f2bf(O[nf][r] * invl[r]);
}

// ---------------------------------------------------------------------------
extern "C" void kernel_launch(void* const* d_in, const int* in_sizes, int n_in,
                              void* d_out, int out_size, void* d_ws, size_t ws_size,
                              hipStream_t stream)
{
    (void)in_sizes; (void)n_in; (void)out_size; (void)ws_size;
    const float* x      = (const float*)d_in[0];
    const float* wq     = (const float*)d_in[1];
    const float* wk     = (const float*)d_in[2];
    const float* wv     = (const float*)d_in[3];
    const float* w_proj = (const float*)d_in[4];
    const float* b_proj = (const float*)d_in[5];
    const float* w1     = (const float*)d_in[6];
    const float* b1     = (const float*)d_in[7];
    const float* w2     = (const float*)d_in[8];
    const float* b2     = (const float*)d_in[9];
    const float* g1     = (const float*)d_in[10];
    const float* be1    = (const float*)d_in[11];
    const float* g2     = (const float*)d_in[12];
    const float* be2    = (const float*)d_in[13];
    float* out = (float*)d_out;

    const size_t MB = (size_t)1024 * 1024;
    char* wsp = (char*)d_ws;
    u16* h_hi  = (u16*)(wsp + 0 * MB);      // 16 MiB (reused as f2)
    u16* h_lo  = (u16*)(wsp + 16 * MB);     // 16 MiB (reused as ao)
    u16* qk_hi = (u16*)(wsp + 32 * MB);     // 32 MiB (8192 x 2048 bf16)
    u16* qk_lo = (u16*)(wsp + 64 * MB);     // 32 MiB
    u16* vtr   = (u16*)(wsp + 112 * MB);    // 16 MiB (per-head V^T)
    float* y   = (float*)(wsp + 128 * MB);  // 32 MiB f32
    u16* wqkT_hi = (u16*)(wsp + 160 * MB);  // 4 MiB (2048 x 1024 bf16)
    u16* wqkT_lo = (u16*)(wsp + 164 * MB);  // 4 MiB
    u16* wvT     = (u16*)(wsp + 168 * MB);  // 2 MiB
    u16* wpT     = (u16*)(wsp + 170 * MB);  // 2 MiB
    u16* w1T     = (u16*)(wsp + 172 * MB);  // 8 MiB
    u16* w2T     = (u16*)(wsp + 180 * MB);  // 8 MiB
    u16* f2  = h_hi;
    u16* ao  = h_lo;
    u16* act = qk_hi;   // 64 MiB span (qk_hi + qk_lo), free after attn

    dim3 blk(256);

    // weight repacks: 2 launches
    repack_qkv<<<dim3(3, 16, 16), blk, 0, stream>>>(wq, wk, wv, wqkT_hi, wqkT_lo, wvT);
    repack_w<<<dim3(2304), blk, 0, stream>>>(w_proj, wpT, w1, w1T, w2, w2T);

    // LN1 (split output), 4 rows/block
    ln_split<<<2048, blk, 0, stream>>>(x, g1, be1, h_hi, h_lo);

    // Q+K stacked: 8-phase 256^2 with interleaved bf16x3 (K'=3072), 256 blocks
    gemm8<1, 1><<<dim3(256), dim3(512), 0, stream>>>(h_hi, h_lo, wqkT_hi, wqkT_lo,
                                                     qk_hi, qk_lo, nullptr,
                                                     8192, 2048, 1024, 8);
    // V^T direct with per-head scatter epilogue (FLAG 16)
    gemm_bt<16><<<dim3(64, 8), blk, 0, stream>>>(wvT, h_hi, vtr, nullptr, nullptr, 1024, 8192, 1024);

    // attention (2048 blocks x 256 thr, XCD-chunked + qt-reversed)
    attn<<<dim3(2048), blk, 0, stream>>>(qk_hi, qk_lo, vtr, ao);

    // proj + bias + residual(x) -> y (f32)
    gemm_bt<1 | 4 | 8><<<dim3(8, 64), blk, 0, stream>>>(ao, wpT, y, b_proj, x, 8192, 1024, 1024);

    // LN2, 4 rows/block
    ln_split<<<2048, blk, 0, stream>>>(y, g2, be2, f2, nullptr);

    // FFN1: 8-phase 256^2 (bias+relu, bf16 out), 512 blocks
    gemm8<0, 0><<<dim3(512), dim3(512), 0, stream>>>(f2, nullptr, w1T, nullptr,
                                                     act, nullptr, b1,
                                                     8192, 4096, 1024, 16);
    // FFN2 (+bias+residual, f32 out)
    gemm_bt<1 | 4 | 8><<<dim3(8, 64), blk, 0, stream>>>(act, w2T, out, b2, y, 8192, 1024, 4096);
}

// Round 18
// 483.723 us; speedup vs baseline: 1.0139x; 1.0139x over previous
//
#include <hip/hip_runtime.h>

// ---------------------------------------------------------------------------
// TransformerBlock: B=8, T=1024, E=1024, H=16, HS=64, FF=4096
// bf16 MFMA (16x16x32) everywhere; bf16x3 split (hi/lo) on LN1->Q,K and QK^T
// because the reference scales scores by sqrt(T)=32 (near-one-hot softmax).
// R18: revert gemm_bt to BKT=32 (R16 config, 486us best). R17's BKT=64
// regressed (+4us): halving barrier events also halved latency-hiding
// granularity at 2 blocks/CU - same trade-off class that sank R14.
// This is the banked best configuration.
// ---------------------------------------------------------------------------

typedef unsigned short u16;
typedef __attribute__((ext_vector_type(8))) short  bfx8;
typedef __attribute__((ext_vector_type(4))) float  f32x4;
typedef __attribute__((ext_vector_type(4))) unsigned short u16v4;

#define MFMA16 __builtin_amdgcn_mfma_f32_16x16x32_bf16

__device__ __forceinline__ u16 f2bf(float f) {
    union { float f; unsigned u; } c; c.f = f;
    unsigned r = c.u + 0x7fffu + ((c.u >> 16) & 1u);
    return (u16)(r >> 16);
}
__device__ __forceinline__ float bf2f(u16 b) {
    union { unsigned u; float f; } c; c.u = ((unsigned)b) << 16; return c.f;
}
__device__ __forceinline__ float exp2_fast(float x) {
    float r; asm("v_exp_f32 %0, %1" : "=v"(r) : "v"(x)); return r;
}

__device__ __forceinline__ void gl_lds16(const void* g, void* l) {
    void* gg = (void*)g;
    __builtin_amdgcn_global_load_lds(
        (__attribute__((address_space(1))) void*)gg,
        (__attribute__((address_space(3))) void*)l,
        16, 0, 0);
}

// ---------------------------------------------------------------------------
// Shared transpose body: one 64x64 tile. src f32 [R][C] row-major at
// (row0,col0); dst bf16 [C][R] with row stride OS at (col0,row0).
// ---------------------------------------------------------------------------
__device__ __forceinline__ void transpose_tile(const float* __restrict__ src,
                                               u16* __restrict__ dhi,
                                               u16* __restrict__ dlo,
                                               int C, int OS, int row0, int col0)
{
    __shared__ float t[64][65];
    const int tid = threadIdx.x;
    const float* s = src + ((size_t)row0) * C + col0;
    const size_t obase = ((size_t)col0) * OS + row0;
    {
        const int r = tid >> 2, c4 = (tid & 3) * 16;
#pragma unroll
        for (int k = 0; k < 4; ++k) {
            float4 f = *(const float4*)(s + (size_t)r * C + c4 + k * 4);
            t[r][c4 + k*4 + 0] = f.x; t[r][c4 + k*4 + 1] = f.y;
            t[r][c4 + k*4 + 2] = f.z; t[r][c4 + k*4 + 3] = f.w;
        }
    }
    __syncthreads();
    {
        const int c = tid >> 2, r4 = (tid & 3) * 16;
        bfx8 h0, h1, l0, l1;
#pragma unroll
        for (int k = 0; k < 8; ++k) {
            float v0 = t[r4 + k][c];
            float v1 = t[r4 + 8 + k][c];
            u16 a = f2bf(v0), b = f2bf(v1);
            h0[k] = (short)a; h1[k] = (short)b;
            l0[k] = (short)f2bf(v0 - bf2f(a));
            l1[k] = (short)f2bf(v1 - bf2f(b));
        }
        u16* d = dhi + obase + (size_t)c * OS + r4;
        *(bfx8*)d = h0; *(bfx8*)(d + 8) = h1;
        if (dlo) {
            u16* d2 = dlo + obase + (size_t)c * OS + r4;
            *(bfx8*)d2 = l0; *(bfx8*)(d2 + 8) = l1;
        }
    }
}

// ---------------------------------------------------------------------------
// repack_qkv: wq/wk/wv [H=16][E=1024][HS=64] -> wqkT_hi/lo rows 0..2047 and
// wvT (no split). Grid (3, 16 row-tiles, 16 heads); x selects the weight.
// ---------------------------------------------------------------------------
__global__ __launch_bounds__(256)
void repack_qkv(const float* __restrict__ wq, const float* __restrict__ wk,
                const float* __restrict__ wv, u16* __restrict__ qkhi,
                u16* __restrict__ qklo, u16* __restrict__ vT)
{
    const int sel = blockIdx.x;       // 0=wq 1=wk 2=wv
    const int yt  = blockIdx.y;
    const int hh  = blockIdx.z;
    const float* src = (sel == 0) ? wq : (sel == 1) ? wk : wv;
    u16* dhi = (sel == 0) ? qkhi : (sel == 1) ? (qkhi + (size_t)1024 * 1024) : vT;
    u16* dlo = (sel == 0) ? qklo : (sel == 1) ? (qklo + (size_t)1024 * 1024) : nullptr;
    transpose_tile(src + (size_t)hh * 65536,
                   dhi + (size_t)hh * 65536,
                   dlo ? dlo + (size_t)hh * 65536 : nullptr,
                   64, 1024, yt * 64, 0);
}

// ---------------------------------------------------------------------------
// repack_w: w_proj (256 tiles) + w1 (1024) + w2 (1024). Flat 2304-block grid.
// ---------------------------------------------------------------------------
__global__ __launch_bounds__(256)
void repack_w(const float* __restrict__ wp, u16* __restrict__ wpT,
              const float* __restrict__ w1, u16* __restrict__ w1T,
              const float* __restrict__ w2, u16* __restrict__ w2T)
{
    const int id = blockIdx.x;
    if (id < 256) {
        const int xt = id & 15, yt = id >> 4;
        transpose_tile(wp, wpT, nullptr, 1024, 1024, yt * 64, xt * 64);
    } else if (id < 1280) {
        const int i2 = id - 256;
        const int xt = i2 & 63, yt = i2 >> 6;
        transpose_tile(w1, w1T, nullptr, 4096, 1024, yt * 64, xt * 64);
    } else {
        const int i2 = id - 1280;
        const int xt = i2 & 15, yt = i2 >> 4;
        transpose_tile(w2, w2T, nullptr, 1024, 4096, yt * 64, xt * 64);
    }
}

// ---------------------------------------------------------------------------
// LayerNorm over E=1024. 4 rows per 256-thr block, one wave per row.
// ---------------------------------------------------------------------------
__global__ __launch_bounds__(256)
void ln_split(const float* __restrict__ x, const float* __restrict__ g,
              const float* __restrict__ be, u16* __restrict__ hhi,
              u16* __restrict__ hlo)
{
    const int lane = threadIdx.x & 63;
    const int row  = blockIdx.x * 4 + (threadIdx.x >> 6);
    const float* xr = x + (size_t)row * 1024;

    float4 v[4];
    float s = 0.f, s2 = 0.f;
#pragma unroll
    for (int i = 0; i < 4; ++i) {
        v[i] = *(const float4*)(xr + i * 256 + lane * 4);
        s  += v[i].x + v[i].y + v[i].z + v[i].w;
        s2 += v[i].x*v[i].x + v[i].y*v[i].y + v[i].z*v[i].z + v[i].w*v[i].w;
    }
#pragma unroll
    for (int m = 32; m >= 1; m >>= 1) {
        s  += __shfl_xor(s,  m, 64);
        s2 += __shfl_xor(s2, m, 64);
    }
    const float mean = s * (1.0f / 1024.0f);
    const float var  = s2 * (1.0f / 1024.0f) - mean * mean;
    const float inv  = rsqrtf(var + 1e-5f);

#pragma unroll
    for (int i = 0; i < 4; ++i) {
        const int col0 = i * 256 + lane * 4;
        float hv[4];
        hv[0] = (v[i].x - mean) * inv * g[col0+0] + be[col0+0];
        hv[1] = (v[i].y - mean) * inv * g[col0+1] + be[col0+1];
        hv[2] = (v[i].z - mean) * inv * g[col0+2] + be[col0+2];
        hv[3] = (v[i].w - mean) * inv * g[col0+3] + be[col0+3];
        u16v4 hb, lb;
#pragma unroll
        for (int k = 0; k < 4; ++k) {
            u16 a = f2bf(hv[k]);
            hb[k] = a;
            lb[k] = f2bf(hv[k] - bf2f(a));
        }
        *(u16v4*)(hhi + (size_t)row * 1024 + col0) = hb;
        if (hlo) *(u16v4*)(hlo + (size_t)row * 1024 + col0) = lb;
    }
}

// ---------------------------------------------------------------------------
// GEMM (m97 128x128, BKT=32): C = A @ Bt^T.
// FLAGS: 1=bias 2=relu 4=residual 8=f32out 16=vT-scatter.
// T1 bijective XCD-chunked block swizzle (nwg % 8 == 0).
// ---------------------------------------------------------------------------
#define BM 128
#define BN 128
#define BKT 32

template<int FLAGS>
__global__ __launch_bounds__(256, 2)
void gemm_bt(const u16* __restrict__ A, const u16* __restrict__ Bt,
             void* __restrict__ Cout, const float* __restrict__ bias,
             const float* __restrict__ res, int M, int N, int K)
{
    __shared__ u16 As[BM * BKT];
    __shared__ u16 Bs[BN * BKT];
    const int tid  = threadIdx.x;
    const int lane = tid & 63, wave = tid >> 6;
    const int wr = wave >> 1, wc = wave & 1;
    const int li = lane & 15, lg = lane >> 4;

    const int nbx = gridDim.x;
    const int nwg = nbx * gridDim.y;
    const int cpx = nwg >> 3;
    int bid = blockIdx.y * nbx + blockIdx.x;
    bid = (bid & 7) * cpx + (bid >> 3);
    const size_t m0 = (size_t)(bid / nbx) * BM;
    const size_t n0 = (size_t)(bid % nbx) * BN;
    f32x4 acc[4][4] = {};

    const int slot0 = tid, slot1 = tid + 256;
    const int r0 = slot0 >> 2, kc0 = (slot0 & 3) * 8;
    const int r1 = slot1 >> 2, kc1 = (slot1 & 3) * 8;

    for (int kt = 0; kt < K; kt += BKT) {
        __syncthreads();
        gl_lds16(A  + (m0 + r0) * K + kt + kc0, As + slot0 * 8);
        gl_lds16(Bt + (n0 + r0) * K + kt + kc0, Bs + slot0 * 8);
        gl_lds16(A  + (m0 + r1) * K + kt + kc1, As + slot1 * 8);
        gl_lds16(Bt + (n0 + r1) * K + kt + kc1, Bs + slot1 * 8);
        __syncthreads();
        bfx8 af[4], bfr[4];
#pragma unroll
        for (int i = 0; i < 4; ++i)
            af[i] = *(const bfx8*)&As[(wr * 64 + i * 16 + li) * BKT + lg * 8];
#pragma unroll
        for (int j = 0; j < 4; ++j)
            bfr[j] = *(const bfx8*)&Bs[(wc * 64 + j * 16 + li) * BKT + lg * 8];
#pragma unroll
        for (int i = 0; i < 4; ++i)
#pragma unroll
            for (int j = 0; j < 4; ++j)
                acc[i][j] = MFMA16(af[i], bfr[j], acc[i][j], 0, 0, 0);
    }

    float* Cf = (float*)Cout;
    u16*   Cb = (u16*)Cout;
#pragma unroll
    for (int i = 0; i < 4; ++i)
#pragma unroll
        for (int j = 0; j < 4; ++j)
#pragma unroll
            for (int r = 0; r < 4; ++r) {
                const size_t row = m0 + wr * 64 + i * 16 + lg * 4 + r;
                const size_t col = n0 + wc * 64 + j * 16 + li;
                float v = acc[i][j][r];
                if (FLAGS & 1) v += bias[col];
                if (FLAGS & 2) v = fmaxf(v, 0.0f);
                if (FLAGS & 4) v += res[row * (size_t)N + col];
                if (FLAGS & 16) {
                    const size_t drow = ((col >> 10) * 16 + (row >> 6)) * 64 + (row & 63);
                    Cb[drow * 1024 + (col & 1023)] = f2bf(v);
                } else if (FLAGS & 8) {
                    Cf[row * (size_t)N + col] = v;
                } else {
                    Cb[row * (size_t)N + col] = f2bf(v);
                }
            }
}

// ---------------------------------------------------------------------------
// 8-phase 256x256 GEMM core (T2+T3+T4+T5). EPI: 0 = bias+relu bf16 out,
// 1 = hi/lo split bf16 out. SPLIT3: fold bf16x3 into K'=3K with passes
// INTERLEAVED per k (j -> k=j/3, p=j%3).
// ---------------------------------------------------------------------------
template<int EPI, int SPLIT3>
__global__ __launch_bounds__(512, 2)
void gemm8(const u16* __restrict__ A, const u16* __restrict__ Al,
           const u16* __restrict__ Bt, const u16* __restrict__ Bl,
           u16* __restrict__ C, u16* __restrict__ Clo,
           const float* __restrict__ bias,
           int M, int N, int K, int NBX)
{
    __shared__ u16 Asl[2][2][128 * 64];
    __shared__ u16 Bsl[2][2][128 * 64];
    const int tid = threadIdx.x;
    const int lane = tid & 63, wave = tid >> 6;
    const int wr = wave >> 2, wc = wave & 3;
    const int li = lane & 15, lg = lane >> 4;

    const int bid = blockIdx.x;
    const int nwg = gridDim.x;
    const int cpx = nwg >> 3;
    const int swz = (bid & 7) * cpx + (bid >> 3);
    const int bx = swz % NBX, by = swz / NBX;
    const size_t m0 = (size_t)by * 256, n0 = (size_t)bx * 256;

    char* ldsA = (char*)&Asl[0][0][0];
    char* ldsB = (char*)&Bsl[0][0][0];

    const int KT = K >> 6;

    auto stageA = [&](int j, int h) {
        const u16* src = A;
        int jj = j;
        if (SPLIT3) {
            const int k = j / 3, p = j - 3 * k;
            src = (p == 2) ? Al : A;
            jj = k;
        }
#pragma unroll
        for (int site = 0; site < 2; ++site) {
            const int s = tid + site * 512;
            const int r = s >> 3;
            const int cb = ((s & 7) << 4) ^ ((r & 7) << 4);
            gl_lds16((const char*)(src + (m0 + h * 128 + r) * (size_t)K + (size_t)jj * 64) + cb,
                     ldsA + ((j & 1) * 2 + h) * 16384 + s * 16);
        }
    };
    auto stageB = [&](int j, int h) {
        const u16* src = Bt;
        int jj = j;
        if (SPLIT3) {
            const int k = j / 3, p = j - 3 * k;
            src = (p == 1) ? Bl : Bt;
            jj = k;
        }
#pragma unroll
        for (int site = 0; site < 2; ++site) {
            const int s = tid + site * 512;
            const int r = s >> 3;
            const int cb = ((s & 7) << 4) ^ ((r & 7) << 4);
            gl_lds16((const char*)(src + (n0 + h * 128 + r) * (size_t)K + (size_t)jj * 64) + cb,
                     ldsB + ((j & 1) * 2 + h) * 16384 + s * 16);
        }
    };

    const int lsw = (li & 7) << 4;
    const int aHalfBase = wr * 16384;
    const int bHalfBase = (wc >> 1) * 16384;
    const int bRow0 = (wc & 1) * 64;

    f32x4 acc[8][4] = {};
    const int NT = SPLIT3 ? 3 * KT : KT;
    const int NI = NT >> 1;

    stageA(0, 0); stageA(0, 1); stageB(0, 0); stageB(0, 1);
    stageB(1, 0); stageB(1, 1);
    asm volatile("s_waitcnt vmcnt(0)" ::: "memory");
    __builtin_amdgcn_sched_barrier(0);
    __builtin_amdgcn_s_barrier();
    __builtin_amdgcn_sched_barrier(0);

    for (int t = 0; t < NI; ++t) {
        const bool more = (t + 1 < NI);
#pragma unroll
        for (int half = 0; half < 2; ++half) {
            const int buf = half;
            const int abase = buf * 32768 + aHalfBase;
            const int bbase = buf * 32768 + bHalfBase;
            bfx8 bfr[4][2];
#pragma unroll
            for (int q = 0; q < 4; ++q) {
                if (q == 0) {
#pragma unroll
                    for (int nf = 0; nf < 4; ++nf)
#pragma unroll
                        for (int ks = 0; ks < 2; ++ks)
                            bfr[nf][ks] = *(const bfx8*)(ldsB + bbase
                                + (bRow0 + nf * 16 + li) * 128
                                + ((ks * 64 + lg * 16) ^ lsw));
                }
                bfx8 afr[2][2];
#pragma unroll
                for (int m = 0; m < 2; ++m)
#pragma unroll
                    for (int ks = 0; ks < 2; ++ks)
                        afr[m][ks] = *(const bfx8*)(ldsA + abase
                            + ((2 * q + m) * 16 + li) * 128
                            + ((ks * 64 + lg * 16) ^ lsw));

                if (half == 0) {
                    if (q == 0) stageA(2 * t + 1, 0);
                    else if (q == 1) stageA(2 * t + 1, 1);
                    else if (q == 2) { if (more) stageB(2 * t + 2, 0); }
                    else             { if (more) stageB(2 * t + 2, 1); }
                } else {
                    if (q == 0)      { if (more) stageA(2 * t + 2, 0); }
                    else if (q == 1) { if (more) stageA(2 * t + 2, 1); }
                    else if (q == 2) { if (more) stageB(2 * t + 3, 0); }
                    else             { if (more) stageB(2 * t + 3, 1); }
                }

                __builtin_amdgcn_sched_barrier(0);
                __builtin_amdgcn_s_barrier();
                asm volatile("s_waitcnt lgkmcnt(0)" ::: "memory");
                __builtin_amdgcn_sched_barrier(0);
                __builtin_amdgcn_s_setprio(1);
#pragma unroll
                for (int ks = 0; ks < 2; ++ks)
#pragma unroll
                    for (int m = 0; m < 2; ++m)
#pragma unroll
                        for (int nf = 0; nf < 4; ++nf)
                            acc[2 * q + m][nf] = MFMA16(afr[m][ks], bfr[nf][ks],
                                                        acc[2 * q + m][nf], 0, 0, 0);
                __builtin_amdgcn_s_setprio(0);
                __builtin_amdgcn_sched_barrier(0);
                if (q == 3) {
                    if (half == 0) {
                        if (more) { asm volatile("s_waitcnt vmcnt(4)" ::: "memory"); }
                        else      { asm volatile("s_waitcnt vmcnt(0)" ::: "memory"); }
                    } else if (more) {
                        asm volatile("s_waitcnt vmcnt(4)" ::: "memory");
                    }
                    __builtin_amdgcn_sched_barrier(0);
                }
                __builtin_amdgcn_s_barrier();
                __builtin_amdgcn_sched_barrier(0);
            }
        }
    }

#pragma unroll
    for (int i = 0; i < 8; ++i)
#pragma unroll
        for (int nf = 0; nf < 4; ++nf)
#pragma unroll
            for (int r = 0; r < 4; ++r) {
                const size_t row = m0 + wr * 128 + i * 16 + lg * 4 + r;
                const size_t col = n0 + wc * 64 + nf * 16 + li;
                if (EPI == 0) {
                    float v = acc[i][nf][r] + bias[col];
                    v = fmaxf(v, 0.0f);
                    C[row * (size_t)N + col] = f2bf(v);
                } else {
                    const float v = acc[i][nf][r];
                    const u16 hi = f2bf(v);
                    C[row * (size_t)N + col]   = hi;
                    Clo[row * (size_t)N + col] = f2bf(v - bf2f(hi));
                }
            }
}

// ---------------------------------------------------------------------------
// Causal flash attention (R13 config, proven ~120us), 4 waves / 64 Q-rows,
// 2048 blocks, XCD-chunked + qt-reversed. Q/K from STACKED qk buffers
// (row stride 2048). K hi/lo double-buffered in LDS (XOR swizzle);
// V -> regs at iter top; counted vmcnt; l via ones-MFMA; defer-max;
// Pl swizzled [64][64]. LDS 40960 -> 3 blocks/CU. (256,3): lower caps
// spill (R5-R7); bigger tiles lose occupancy (R14).
// ---------------------------------------------------------------------------
#define QKS 2048

__global__ __launch_bounds__(256, 3)
void attn(const u16* __restrict__ qkhi, const u16* __restrict__ qklo,
          const u16* __restrict__ vt, u16* __restrict__ ao)
{
    const int id  = blockIdx.x;
    const int swz = (id & 7) * 256 + (id >> 3);
    const int qt  = 15 - (swz & 15);
    const int h   = (swz >> 4) & 15;
    const int b   = swz >> 8;

    const int tid = threadIdx.x;
    const int wave = tid >> 6, lane = tid & 63;
    const int li = lane & 15, lg = lane >> 4;

    __shared__ u16 KsHi[2][4096];
    __shared__ u16 KsLo[2][4096];
    __shared__ u16 Pl[64 * 64];

    const size_t qrow = (size_t)b * 1024 + qt * 64 + wave * 16 + li;
    const size_t qoff = qrow * QKS + h * 64 + lg * 8;
    const bfx8 qh0 = *(const bfx8*)(qkhi + qoff);
    const bfx8 qh1 = *(const bfx8*)(qkhi + qoff + 32);
    const bfx8 ql0 = *(const bfx8*)(qklo + qoff);
    const bfx8 ql1 = *(const bfx8*)(qklo + qoff + 32);

    bfx8 onesf;
#pragma unroll
    for (int k = 0; k < 8; ++k) onesf[k] = (short)0x3F80;

    f32x4 O[4] = {};
    f32x4 O5 = {0.f, 0.f, 0.f, 0.f};
    float mrow[4] = {-3e38f, -3e38f, -3e38f, -3e38f};

    const u16* kh_base = qkhi + ((size_t)b * 1024) * QKS + 1024 + h * 64;
    const u16* kl_base = qklo + ((size_t)b * 1024) * QKS + 1024 + h * 64;
    const u16* v_base  = vt + ((size_t)(b * 16 + h) * 64) * 1024;

    auto stageK = [&](int kt, int bufIdx) {
#pragma unroll
        for (int site = 0; site < 2; ++site) {
            const int s = tid + site * 256;
            const int r = s >> 3;
            const int cb = (((s & 7) << 4) ^ ((r & 7) << 4));
            const size_t go = ((size_t)(kt * 64 + r)) * QKS;
            gl_lds16((const char*)(kh_base + go) + cb, (char*)&KsHi[bufIdx][0] + s * 16);
            gl_lds16((const char*)(kl_base + go) + cb, (char*)&KsLo[bufIdx][0] + s * 16);
        }
    };

    const int rswz = (li & 7) << 4;
    char* pband = (char*)&Pl[0] + wave * 2048;

    stageK(0, 0);

    for (int kt = 0; kt <= qt; ++kt) {
        const int cur = kt & 1;

        bfx8 vld[2][4];
#pragma unroll
        for (int nf = 0; nf < 4; ++nf) {
            const u16* vr = v_base + ((size_t)(nf * 16 + li)) * 1024 + kt * 64 + lg * 8;
            vld[0][nf] = *(const bfx8*)vr;
            vld[1][nf] = *(const bfx8*)(vr + 32);
        }

        if (kt < qt) {
            stageK(kt + 1, cur ^ 1);
            asm volatile("s_waitcnt vmcnt(12)" ::: "memory");
        } else {
            asm volatile("s_waitcnt vmcnt(8)" ::: "memory");
        }
        __builtin_amdgcn_sched_barrier(0);
        __builtin_amdgcn_s_barrier();
        __builtin_amdgcn_sched_barrier(0);

        float sv[4][4];
        const char* khc = (const char*)&KsHi[cur][0];
        const char* klc = (const char*)&KsLo[cur][0];
#pragma unroll
        for (int nf = 0; nf < 4; ++nf) {
            const int rb = (nf * 16 + li) * 128;
            bfx8 kh0v = *(const bfx8*)(khc + rb + (((lg * 16) + 0 ) ^ rswz));
            bfx8 kh1v = *(const bfx8*)(khc + rb + (((lg * 16) + 64) ^ rswz));
            bfx8 kl0v = *(const bfx8*)(klc + rb + (((lg * 16) + 0 ) ^ rswz));
            bfx8 kl1v = *(const bfx8*)(klc + rb + (((lg * 16) + 64) ^ rswz));
            f32x4 a = {0.f, 0.f, 0.f, 0.f};
            a = MFMA16(qh0, kh0v, a, 0, 0, 0);
            a = MFMA16(qh1, kh1v, a, 0, 0, 0);
            a = MFMA16(qh0, kl0v, a, 0, 0, 0);
            a = MFMA16(qh1, kl1v, a, 0, 0, 0);
            a = MFMA16(ql0, kh0v, a, 0, 0, 0);
            a = MFMA16(ql1, kh1v, a, 0, 0, 0);
#pragma unroll
            for (int r = 0; r < 4; ++r) sv[nf][r] = a[r];
        }

        asm volatile("s_waitcnt lgkmcnt(0)" ::: "memory");
        __builtin_amdgcn_sched_barrier(0);
        __builtin_amdgcn_s_barrier();
        __builtin_amdgcn_sched_barrier(0);

        const float SC = 46.16624130844683f;
        float pmax[4] = {-3e38f, -3e38f, -3e38f, -3e38f};
        if (kt == qt) {
            const int rowg = qt * 64 + wave * 16 + lg * 4;
            const int colg = kt * 64 + li;
#pragma unroll
            for (int nf = 0; nf < 4; ++nf)
#pragma unroll
                for (int r = 0; r < 4; ++r) {
                    float x2 = sv[nf][r] * SC;
                    if (colg + nf * 16 > rowg + r) x2 = -3e38f;
                    sv[nf][r] = x2;
                    pmax[r] = fmaxf(pmax[r], x2);
                }
        } else {
#pragma unroll
            for (int nf = 0; nf < 4; ++nf)
#pragma unroll
                for (int r = 0; r < 4; ++r) {
                    const float x2 = sv[nf][r] * SC;
                    sv[nf][r] = x2;
                    pmax[r] = fmaxf(pmax[r], x2);
                }
        }
#pragma unroll
        for (int msk = 1; msk < 16; msk <<= 1)
#pragma unroll
            for (int r = 0; r < 4; ++r)
                pmax[r] = fmaxf(pmax[r], __shfl_xor(pmax[r], msk, 64));

        const bool grow = !__all((pmax[0] - mrow[0] <= 11.5416f) &&
                                 (pmax[1] - mrow[1] <= 11.5416f) &&
                                 (pmax[2] - mrow[2] <= 11.5416f) &&
                                 (pmax[3] - mrow[3] <= 11.5416f));
        if (grow) {
            float alr[4];
#pragma unroll
            for (int r = 0; r < 4; ++r) {
                const float mnew = fmaxf(mrow[r], pmax[r]);
                alr[r] = exp2_fast(mrow[r] - mnew);
                mrow[r] = mnew;
            }
#pragma unroll
            for (int nf = 0; nf < 4; ++nf)
#pragma unroll
                for (int r = 0; r < 4; ++r)
                    O[nf][r] *= alr[r];
#pragma unroll
            for (int r = 0; r < 4; ++r)
                O5[r] *= alr[r];
        }

#pragma unroll
        for (int nf = 0; nf < 4; ++nf)
#pragma unroll
            for (int r = 0; r < 4; ++r) {
                const int prow = lg * 4 + r;
                const int pb = prow * 128 + ((((nf * 16 + li) * 2)) ^ ((prow & 7) << 4));
                *(u16*)(pband + pb) = f2bf(exp2_fast(sv[nf][r] - mrow[r]));
            }

#pragma unroll
        for (int ku = 0; ku < 2; ++ku) {
            bfx8 pf = *(const bfx8*)(pband + li * 128
                                     + ((ku * 64 + lg * 16) ^ ((li & 7) << 4)));
#pragma unroll
            for (int nf = 0; nf < 4; ++nf)
                O[nf] = MFMA16(pf, vld[ku][nf], O[nf], 0, 0, 0);
            O5 = MFMA16(pf, onesf, O5, 0, 0, 0);
        }
    }

    float invl[4];
#pragma unroll
    for (int r = 0; r < 4; ++r) invl[r] = 1.0f / O5[r];
    const size_t orow = (size_t)b * 1024 + qt * 64 + wave * 16 + lg * 4;
#pragma unroll
    for (int nf = 0; nf < 4; ++nf)
#pragma unroll
        for (int r = 0; r < 4; ++r)
            ao[(orow + r) * 1024 + h * 64 + nf * 16 + li] = f2bf(O[nf][r] * invl[r]);
}

// ---------------------------------------------------------------------------
extern "C" void kernel_launch(void* const* d_in, const int* in_sizes, int n_in,
                              void* d_out, int out_size, void* d_ws, size_t ws_size,
                              hipStream_t stream)
{
    (void)in_sizes; (void)n_in; (void)out_size; (void)ws_size;
    const float* x      = (const float*)d_in[0];
    const float* wq     = (const float*)d_in[1];
    const float* wk     = (const float*)d_in[2];
    const float* wv     = (const float*)d_in[3];
    const float* w_proj = (const float*)d_in[4];
    const float* b_proj = (const float*)d_in[5];
    const float* w1     = (const float*)d_in[6];
    const float* b1     = (const float*)d_in[7];
    const float* w2     = (const float*)d_in[8];
    const float* b2     = (const float*)d_in[9];
    const float* g1     = (const float*)d_in[10];
    const float* be1    = (const float*)d_in[11];
    const float* g2     = (const float*)d_in[12];
    const float* be2    = (const float*)d_in[13];
    float* out = (float*)d_out;

    const size_t MB = (size_t)1024 * 1024;
    char* wsp = (char*)d_ws;
    u16* h_hi  = (u16*)(wsp + 0 * MB);      // 16 MiB (reused as f2)
    u16* h_lo  = (u16*)(wsp + 16 * MB);     // 16 MiB (reused as ao)
    u16* qk_hi = (u16*)(wsp + 32 * MB);     // 32 MiB (8192 x 2048 bf16)
    u16* qk_lo = (u16*)(wsp + 64 * MB);     // 32 MiB
    u16* vtr   = (u16*)(wsp + 112 * MB);    // 16 MiB (per-head V^T)
    float* y   = (float*)(wsp + 128 * MB);  // 32 MiB f32
    u16* wqkT_hi = (u16*)(wsp + 160 * MB);  // 4 MiB (2048 x 1024 bf16)
    u16* wqkT_lo = (u16*)(wsp + 164 * MB);  // 4 MiB
    u16* wvT     = (u16*)(wsp + 168 * MB);  // 2 MiB
    u16* wpT     = (u16*)(wsp + 170 * MB);  // 2 MiB
    u16* w1T     = (u16*)(wsp + 172 * MB);  // 8 MiB
    u16* w2T     = (u16*)(wsp + 180 * MB);  // 8 MiB
    u16* f2  = h_hi;
    u16* ao  = h_lo;
    u16* act = qk_hi;   // 64 MiB span (qk_hi + qk_lo), free after attn

    dim3 blk(256);

    // weight repacks: 2 launches
    repack_qkv<<<dim3(3, 16, 16), blk, 0, stream>>>(wq, wk, wv, wqkT_hi, wqkT_lo, wvT);
    repack_w<<<dim3(2304), blk, 0, stream>>>(w_proj, wpT, w1, w1T, w2, w2T);

    // LN1 (split output), 4 rows/block
    ln_split<<<2048, blk, 0, stream>>>(x, g1, be1, h_hi, h_lo);

    // Q+K stacked: 8-phase 256^2 with interleaved bf16x3 (K'=3072), 256 blocks
    gemm8<1, 1><<<dim3(256), dim3(512), 0, stream>>>(h_hi, h_lo, wqkT_hi, wqkT_lo,
                                                     qk_hi, qk_lo, nullptr,
                                                     8192, 2048, 1024, 8);
    // V^T direct with per-head scatter epilogue (FLAG 16)
    gemm_bt<16><<<dim3(64, 8), blk, 0, stream>>>(wvT, h_hi, vtr, nullptr, nullptr, 1024, 8192, 1024);

    // attention (2048 blocks x 256 thr, XCD-chunked + qt-reversed)
    attn<<<dim3(2048), blk, 0, stream>>>(qk_hi, qk_lo, vtr, ao);

    // proj + bias + residual(x) -> y (f32)
    gemm_bt<1 | 4 | 8><<<dim3(8, 64), blk, 0, stream>>>(ao, wpT, y, b_proj, x, 8192, 1024, 1024);

    // LN2, 4 rows/block
    ln_split<<<2048, blk, 0, stream>>>(y, g2, be2, f2, nullptr);

    // FFN1: 8-phase 256^2 (bias+relu, bf16 out), 512 blocks
    gemm8<0, 0><<<dim3(512), dim3(512), 0, stream>>>(f2, nullptr, w1T, nullptr,
                                                     act, nullptr, b1,
                                                     8192, 4096, 1024, 16);
    // FFN2 (+bias+residual, f32 out)
    gemm_bt<1 | 4 | 8><<<dim3(8, 64), blk, 0, stream>>>(act, w2T, out, b2, y, 8192, 1024, 4096);
}